// Round 12
// baseline (518.172 us; speedup 1.0000x reference)
//
#include <hip/hip_runtime.h>

#define Bn 512
#define Tn 512
#define Dn 64
#define Hn 128
#define Ln 32
#define GXT   4112            // gx t-stride bytes
#define GXBUF (8*GXT)         // bytes per gx buffer (8 timesteps)
#define HRS   320             // h row stride: row0 -> banks 0-15, row1 -> banks 16-31
#define HBUF  (2*HRS)         // bytes per h buffer
#define SCI  (-1.4426950408889634f)   // -log2(e): i,f,o gate row scale
#define SCG  (-2.8853900817779268f)   // -2 log2(e): g gate row scale / tanh(c) runtime scale

#define EXP2F(v) __builtin_amdgcn_exp2f(v)

typedef __attribute__((ext_vector_type(8))) short short8v;
typedef __attribute__((ext_vector_type(4))) float float4v;
typedef __attribute__((ext_vector_type(2))) float float2v;

__device__ __forceinline__ unsigned short f2bf(float f){
  unsigned int u = __float_as_uint(f);
  u += 0x7FFFu + ((u >> 16) & 1u);           // round-to-nearest-even
  return (unsigned short)(u >> 16);
}

__device__ __forceinline__ short8v pack8(float4v a, float4v b){
  short8v r;
  r[0]=(short)f2bf(a[0]); r[1]=(short)f2bf(a[1]);
  r[2]=(short)f2bf(a[2]); r[3]=(short)f2bf(a[3]);
  r[4]=(short)f2bf(b[0]); r[5]=(short)f2bf(b[1]);
  r[6]=(short)f2bf(b[2]); r[7]=(short)f2bf(b[3]);
  return r;
}

// B-fragment (scaled): lane holds scale*W[n=base+(lane&15)][k0 + 8*(lane>>4) + i]
__device__ __forceinline__ short8v load_wfrag(const float* __restrict__ W, int n, int k0, int ldk, float scale){
  const float* p = W + (size_t)n*(size_t)ldk + (size_t)k0;
  float4v a = *(const float4v*)p;
  float4v b = *(const float4v*)(p+4);
  a *= scale; b *= scale;
  return pack8(a,b);
}

__device__ __forceinline__ float4v mfma16(short8v a, short8v b, float4v c){
  return __builtin_amdgcn_mfma_f32_16x16x32_bf16(a, b, c, 0, 0, 0);
}

// Raw barrier: lgkmcnt-only drain (no vmcnt) so global loads/stores stay in flight.
__device__ __forceinline__ void bar_lds(){
  __builtin_amdgcn_sched_barrier(0);
  asm volatile("s_waitcnt lgkmcnt(0)" ::: "memory");
  __builtin_amdgcn_s_barrier();
  __builtin_amdgcn_sched_barrier(0);
}

// ---------------- precompute: W_eff = dW_hh + dW_ih @ oW ; b_eff = bd + dW_ih @ ob ----------------
__global__ __launch_bounds__(256) void weff_kernel(
    const float* __restrict__ dW_ih, const float* __restrict__ dW_hh,
    const float* __restrict__ db_ih, const float* __restrict__ db_hh,
    const float* __restrict__ oW,    const float* __restrict__ ob,
    float* __restrict__ ws)
{
  int id = blockIdx.x*256 + threadIdx.x;
  if (id < 512*128) {
    int n = id >> 7, h = id & 127;
    float s = dW_hh[id];
    #pragma unroll 8
    for (int d = 0; d < Dn; ++d) s += dW_ih[n*Dn + d] * oW[d*Hn + h];
    ws[id] = s;
  } else if (id < 512*128 + 512) {
    int n = id - 512*128;
    float s = db_ih[n] + db_hh[n];
    #pragma unroll 8
    for (int d = 0; d < Dn; ++d) s += dW_ih[n*Dn + d] * ob[d];
    ws[512*128 + n] = s;
  }
}

// ---------------- main fused kernel: 8 waves, 2 rows/block ----------------
__global__ __launch_bounds__(512, 2) void vae_fused(
    const float* __restrict__ x,     const float* __restrict__ eps,
    const float* __restrict__ eW_ih, const float* __restrict__ eW_hh,
    const float* __restrict__ eb_ih, const float* __restrict__ eb_hh,
    const float* __restrict__ muW,   const float* __restrict__ mub,
    const float* __restrict__ lvW,   const float* __restrict__ lvb,
    const float* __restrict__ iW,    const float* __restrict__ ib,
    const float* __restrict__ dW_hh, const float* __restrict__ db_ih,
    const float* __restrict__ db_hh, const float* __restrict__ oW,
    const float* __restrict__ ob,    const float* __restrict__ ws,
    float* __restrict__ out)
{
  __shared__ __align__(16) char gxb[2*GXBUF];     // ~64 KB: double-buffered gx [t][gate][col][r]
  __shared__ __align__(16) char h_lds[2*HBUF];    // 1.25 KB: double-buffered h, 2 rows @ stride 320
  __shared__ __align__(16) float sc_h[2*Hn];
  __shared__ __align__(16) float sc_mu[2*Ln];
  __shared__ __align__(16) float sc_lv[2*Ln];
  __shared__ __align__(16) float sc_z[2*Ln];

  const int tid  = threadIdx.x;
  const int lane = tid & 63;
  const int w    = tid >> 6;           // wave 0..7: owns h-indices [w*16, w*16+16)
  const int m    = lane & 15;          // fragment col (C) / A row
  const int q    = lane >> 4;          // k-group
  const int hrow = m & 1;              // replicated batch row for h/A reads
  const int rsel = q & 1;              // batch row this lane's nonlin chain owns
  const int jown = w*16 + m;           // h-index this lane owns
  const int b0   = blockIdx.x * 2;
  // per-lane LDS pointers (conflict-free layout)
  char* const hw_p  = h_lds + q*HRS + 2*jown;          // h write (valid q<2; q==rsel there)
  const char* const hr_p = h_lds + hrow*HRS + q*16;    // h-frag read base
  const char* const gx2_p = gxb + jown*8;              // gx read base (b64: both rows)
  char* const gwx_p = gxb + jown*8 + q*(2*GXT);        // gx write base (t=2q)

  // ---- zero h buffers ----
  if (tid < (2*HBUF)/4) ((int*)h_lds)[tid] = 0;

  // ---- encoder weights (gate-scaled): tile nt (=gate) -> row n = nt*128 + jown ----
  short8v wih[8];    // [nt*2+kt] : 4H x D
  short8v whh[16];   // [nt*4+kt] : 4H x H
  #pragma unroll
  for (int nt = 0; nt < 4; ++nt) {
    const float sc = (nt == 2) ? SCG : SCI;
    #pragma unroll
    for (int kt = 0; kt < 2; ++kt) wih[nt*2+kt] = load_wfrag(eW_ih, nt*128 + jown, kt*32 + q*8, Dn, sc);
    #pragma unroll
    for (int kt = 0; kt < 4; ++kt) whh[nt*4+kt] = load_wfrag(eW_hh, nt*128 + jown, kt*32 + q*8, Hn, sc);
  }
  float bia[4];
  #pragma unroll
  for (int g = 0; g < 4; ++g)
    bia[g] = (eb_ih[g*128 + jown] + eb_hh[g*128 + jown]) * ((g == 2) ? SCG : SCI);

  // ---- x batch registers: lane (m,q) holds x[b0+(m&1)][tb*8 + (m>>1)][q*8 ..+8, +32..] ----
  const float* xptr = x + (size_t)(b0 + hrow)*Tn*Dn + (size_t)(m>>1)*Dn + q*8;
  float4v xc0,xc1,xc2,xc3, xn0,xn1,xn2,xn3;
  xc0 = *(const float4v*)(xptr+0);  xc1 = *(const float4v*)(xptr+4);
  xc2 = *(const float4v*)(xptr+32); xc3 = *(const float4v*)(xptr+36);
  xptr += 512;                       // now points at tb=1
  int xnext = 1;                     // next tb to load

  float cst = 0.f, hval = 0.f;       // per-lane c/h for (rsel, jown)
  __syncthreads();

#define RH(RB,KB)     (*(const short8v*)(hr_p + (RB)*HBUF + (KB)))
#define RGX2(CB,S,NT) (*(const float2v*)(gx2_p + (CB)*GXBUF + (S)*GXT + (NT)*1024))

  // gx batch for the NEXT 8-step window into buffer PB (bias pre-added; gate-scaled
  // because wih/bia are scaled). C row q*4+j -> (t = 2q+(j>>1), r = j&1).
#define BATCH(PB) do { \
    short8v xf0 = pack8(xc0, xc1); \
    short8v xf1 = pack8(xc2, xc3); \
    if (xnext < 64) { \
      xn0 = *(const float4v*)(xptr+0);  xn1 = *(const float4v*)(xptr+4); \
      xn2 = *(const float4v*)(xptr+32); xn3 = *(const float4v*)(xptr+36); \
      xptr += 512; \
    } \
    ++xnext; \
    float4v zz = {0.f,0.f,0.f,0.f}; \
    __builtin_amdgcn_s_setprio(1); \
    float4v c0_ = mfma16(xf0, wih[0], zz); \
    float4v c1_ = mfma16(xf0, wih[2], zz); \
    float4v c2_ = mfma16(xf0, wih[4], zz); \
    float4v c3_ = mfma16(xf0, wih[6], zz); \
    c0_ = mfma16(xf1, wih[1], c0_); \
    c1_ = mfma16(xf1, wih[3], c1_); \
    c2_ = mfma16(xf1, wih[5], c2_); \
    c3_ = mfma16(xf1, wih[7], c3_); \
    __builtin_amdgcn_s_setprio(0); \
    char* gp = gwx_p + (PB)*GXBUF; \
    *(float2v*)(gp +       0) = (float2v){c0_[0]+bia[0], c0_[1]+bia[0]}; \
    *(float2v*)(gp +    1024) = (float2v){c1_[0]+bia[1], c1_[1]+bia[1]}; \
    *(float2v*)(gp +    2048) = (float2v){c2_[0]+bia[2], c2_[1]+bia[2]}; \
    *(float2v*)(gp +    3072) = (float2v){c3_[0]+bia[3], c3_[1]+bia[3]}; \
    *(float2v*)(gp + GXT +    0) = (float2v){c0_[2]+bia[0], c0_[3]+bia[0]}; \
    *(float2v*)(gp + GXT + 1024) = (float2v){c1_[2]+bia[1], c1_[3]+bia[1]}; \
    *(float2v*)(gp + GXT + 2048) = (float2v){c2_[2]+bia[2], c2_[3]+bia[2]}; \
    *(float2v*)(gp + GXT + 3072) = (float2v){c3_[2]+bia[3], c3_[3]+bia[3]}; \
    xc0=xn0; xc1=xn1; xc2=xn2; xc3=xn3; \
  } while(0)

  // ONE chain per lane; gates arrive PRE-SCALED: sigm = rcp(1+exp2(g')), tanh = 2*rcp(1+exp2(g''))-1.
#define NONLIN1(GI,GF,GG,GO, WB) do { \
    float si = __builtin_amdgcn_rcpf(1.0f + EXP2F(GI)); \
    float sf = __builtin_amdgcn_rcpf(1.0f + EXP2F(GF)); \
    float so = __builtin_amdgcn_rcpf(1.0f + EXP2F(GO)); \
    float tg = 2.0f*__builtin_amdgcn_rcpf(1.0f + EXP2F(GG)) - 1.0f; \
    float c = sf*cst + si*tg; \
    cst = c; \
    float tc = 2.0f*__builtin_amdgcn_rcpf(1.0f + EXP2F(c*SCG)) - 1.0f; \
    hval = so*tc; \
    if (q < 2) *(unsigned short*)(hw_p + (WB)*HBUF) = f2bf(hval); \
  } while(0)

  // gate MFMAs with C initialized from I0..I3 (gx pair or bias splat)
#define HH16(RB, I0,I1,I2,I3) \
    short8v hf0 = RH(RB,0), hf1 = RH(RB,64), hf2 = RH(RB,128), hf3 = RH(RB,192); \
    __builtin_amdgcn_s_setprio(1); \
    float4v a0 = mfma16(hf0, whh[0],  I0); \
    float4v a1 = mfma16(hf0, whh[4],  I1); \
    float4v a2 = mfma16(hf0, whh[8],  I2); \
    float4v a3 = mfma16(hf0, whh[12], I3); \
    a0 = mfma16(hf1, whh[1],  a0); a1 = mfma16(hf1, whh[5],  a1); \
    a2 = mfma16(hf1, whh[9],  a2); a3 = mfma16(hf1, whh[13], a3); \
    a0 = mfma16(hf2, whh[2],  a0); a1 = mfma16(hf2, whh[6],  a1); \
    a2 = mfma16(hf2, whh[10], a2); a3 = mfma16(hf2, whh[14], a3); \
    a0 = mfma16(hf3, whh[3],  a0); a1 = mfma16(hf3, whh[7],  a1); \
    a2 = mfma16(hf3, whh[11], a2); a3 = mfma16(hf3, whh[15], a3); \
    __builtin_amdgcn_s_setprio(0);

#define ENC_BODY(S, CB) \
    float2v g0 = RGX2(CB,S,0), g1 = RGX2(CB,S,1), g2 = RGX2(CB,S,2), g3 = RGX2(CB,S,3); \
    float4v i0 = {g0[0],g0[1],g0[0],g0[1]}; \
    float4v i1 = {g1[0],g1[1],g1[0],g1[1]}; \
    float4v i2 = {g2[0],g2[1],g2[0],g2[1]}; \
    float4v i3 = {g3[0],g3[1],g3[0],g3[1]}; \
    HH16((S)&1, i0,i1,i2,i3); \
    float gi = rsel ? a0[1] : a0[0]; \
    float gf = rsel ? a1[1] : a1[0]; \
    float gg = rsel ? a2[1] : a2[0]; \
    float go = rsel ? a3[1] : a3[0];

#define ENC_STEP(S, CB) do { \
    ENC_BODY(S, CB); \
    NONLIN1(gi, gf, gg, go, ((S)&1)^1); \
    bar_lds(); \
  } while(0)

#define ENC_STEP0(CB, PRODUCE) do { \
    ENC_BODY(0, CB); \
    NONLIN1(gi, gf, gg, go, 1); \
    if (PRODUCE) BATCH((CB)^1); \
    bar_lds(); \
  } while(0)

#define ENC8(CB, PRODUCE) do { \
    ENC_STEP0(CB, PRODUCE); \
    ENC_STEP(1,CB); ENC_STEP(2,CB); ENC_STEP(3,CB); \
    ENC_STEP(4,CB); ENC_STEP(5,CB); ENC_STEP(6,CB); ENC_STEP(7,CB); \
  } while(0)

  // ================= encoder: 64 batches x 8 steps =================
  BATCH(0);            // gx(tb=0) -> buf0; loads x(tb=1)
  bar_lds();
  #pragma unroll 1
  for (int tb2 = 0; tb2 < 32; ++tb2) {
    ENC8(0, 1);                  // consume buf0, produce buf1
    ENC8(1, (tb2 < 31));         // consume buf1, produce buf0, skip last
  }
  // final h in buffer 0; exact f32 copy of owned element in hval (lanes q<2)

  // ================= latent =================
  if (q < 2) sc_h[rsel*Hn + jown] = hval;
  __syncthreads();

  if (tid < 128) {
    const int isLv = tid >> 6;
    const int rr   = (tid >> 5) & 1;
    const int l    = tid & 31;
    const float* Wp = isLv ? lvW : muW;
    float s = isLv ? lvb[l] : mub[l];
    #pragma unroll
    for (int k = 0; k < Hn; k += 4) {
      float4v wv = *(const float4v*)(Wp + l*Hn + k);
      float4v hv = *(const float4v*)(sc_h + rr*Hn + k);
      s += wv[0]*hv[0] + wv[1]*hv[1] + wv[2]*hv[2] + wv[3]*hv[3];
    }
    out[(size_t)Bn*Tn*Dn + (size_t)isLv*Bn*Ln + (size_t)(b0+rr)*Ln + l] = s;
    (isLv ? sc_lv : sc_mu)[rr*Ln + l] = s;
  }
  __syncthreads();

  if (tid < 64) {
    int rr = tid >> 5, l = tid & 31;
    sc_z[rr*Ln+l] = sc_mu[rr*Ln+l] + eps[(size_t)(b0+rr)*Ln + l] * __expf(0.5f * sc_lv[rr*Ln+l]);
  }
  __syncthreads();

  if (tid < 256) { // decoder hidden init (unscaled, it's h not a gate) -> h buffer 0
    int rr = tid >> 7, jj = tid & 127;
    float s = ib[jj];
    #pragma unroll
    for (int l = 0; l < Ln; ++l) s += sc_z[rr*Ln + l] * iW[jj*Ln + l];
    *(unsigned short*)(h_lds + rr*HRS + 2*jj) = f2bf(s);
  }
  cst = 0.f;

  // ---- decoder step-0 weights (dW_hh, bd; gate-scaled) + output-proj fragments (unscaled) ----
  #pragma unroll
  for (int nt = 0; nt < 4; ++nt) {
    const float sc = (nt == 2) ? SCG : SCI;
    #pragma unroll
    for (int kt = 0; kt < 4; ++kt) whh[nt*4+kt] = load_wfrag(dW_hh, nt*128 + jown, kt*32 + q*8, Hn, sc);
  }
  #pragma unroll
  for (int g = 0; g < 4; ++g)
    bia[g] = (db_ih[g*128 + jown] + db_hh[g*128 + jown]) * ((g == 2) ? SCG : SCI);
  const int ocol = (w & 3)*16 + m;
  short8v ow0 = load_wfrag(oW, ocol,  0 + q*8, Hn, 1.0f);
  short8v ow1 = load_wfrag(oW, ocol, 32 + q*8, Hn, 1.0f);
  short8v ow2 = load_wfrag(oW, ocol, 64 + q*8, Hn, 1.0f);
  short8v ow3 = load_wfrag(oW, ocol, 96 + q*8, Hn, 1.0f);
  const float obv = ob[ocol];
  const float4v ob4 = {obv, obv, obv, obv};
  __syncthreads();

  // ---- decoder step 0: gates = h0 @ dW_hh^T + bd (input is zero) ----
  {
    float4v t0 = {bia[0],bia[0],bia[0],bia[0]};
    float4v t1 = {bia[1],bia[1],bia[1],bia[1]};
    float4v t2 = {bia[2],bia[2],bia[2],bia[2]};
    float4v t3 = {bia[3],bia[3],bia[3],bia[3]};
    HH16(0, t0,t1,t2,t3);
    float gi = rsel ? a0[1] : a0[0];
    float gf = rsel ? a1[1] : a1[0];
    float gg = rsel ? a2[1] : a2[0];
    float go = rsel ? a3[1] : a3[0];
    NONLIN1(gi, gf, gg, go, 1);
    bar_lds();
  }

  // ---- switch to folded weights: W_eff = dW_hh + dW_ih@oW ; b_eff (gate-scaled) ----
  {
    const float* weff = ws;
    const float* beff = ws + 512*128;
    #pragma unroll
    for (int nt = 0; nt < 4; ++nt) {
      const float sc = (nt == 2) ? SCG : SCI;
      #pragma unroll
      for (int kt = 0; kt < 4; ++kt) whh[nt*4+kt] = load_wfrag(weff, nt*128 + jown, kt*32 + q*8, Hn, sc);
    }
    #pragma unroll
    for (int g = 0; g < 4; ++g) bia[g] = beff[g*128 + jown] * ((g == 2) ? SCG : SCI);
  }
  const float4v cb0 = {bia[0],bia[0],bia[0],bia[0]};
  const float4v cb1 = {bia[1],bia[1],bia[1],bia[1]};
  const float4v cb2 = {bia[2],bia[2],bia[2],bia[2]};
  const float4v cb3 = {bia[3],bia[3],bia[3],bia[3]};

  float* outp0 = out + (size_t)(b0+0)*Tn*Dn;
  float* outp1 = out + (size_t)(b0+1)*Tn*Dn;

  // y-MFMAs issue right after gate MFMAs (pipe stays fed while gate latency drains);
  // nonlin runs while y-MFMAs complete; store after.
#define DEC_STEP(RB) do { \
    HH16(RB, cb0,cb1,cb2,cb3); \
    float4v ya = ob4; \
    if (w < 4) { \
      __builtin_amdgcn_s_setprio(1); \
      ya = mfma16(hf0, ow0, ya); ya = mfma16(hf1, ow1, ya); \
      ya = mfma16(hf2, ow2, ya); ya = mfma16(hf3, ow3, ya); \
      __builtin_amdgcn_s_setprio(0); \
    } \
    float gi = rsel ? a0[1] : a0[0]; \
    float gf = rsel ? a1[1] : a1[0]; \
    float gg = rsel ? a2[1] : a2[0]; \
    float go = rsel ? a3[1] : a3[0]; \
    NONLIN1(gi, gf, gg, go, (RB)^1); \
    if (w < 4 && q == 0) { outp0[ocol] = ya[0]; outp1[ocol] = ya[1]; } \
    outp0 += Dn; outp1 += Dn; \
    bar_lds(); \
  } while(0)

  // ---- decoder steps 1..511; y(i-1) computed from the same h(i) fragments ----
  #pragma unroll 1
  for (int i = 1; i < Tn-1; i += 2) {
    DEC_STEP(1);
    DEC_STEP(0);
  }
  DEC_STEP(1);

  // ---- epilogue: y(511) from h(512) (buffer 0) ----
  if (w < 4) {
    short8v hf0 = RH(0,0), hf1 = RH(0,64), hf2 = RH(0,128), hf3 = RH(0,192);
    float4v ya = ob4;
    ya = mfma16(hf0, ow0, ya); ya = mfma16(hf1, ow1, ya);
    ya = mfma16(hf2, ow2, ya); ya = mfma16(hf3, ow3, ya);
    if (q == 0) {
      outp0[ocol] = ya[0];
      outp1[ocol] = ya[1];
    }
  }
#undef DEC_STEP
#undef ENC8
#undef ENC_STEP0
#undef ENC_STEP
#undef ENC_BODY
#undef HH16
#undef NONLIN1
#undef BATCH
#undef RGX2
#undef RH
}

extern "C" void kernel_launch(void* const* d_in, const int* in_sizes, int n_in,
                              void* d_out, int out_size, void* d_ws, size_t ws_size,
                              hipStream_t stream) {
  (void)in_sizes; (void)n_in; (void)ws_size; (void)out_size;
  const float* x     = (const float*)d_in[0];
  const float* eps   = (const float*)d_in[1];
  const float* eW_ih = (const float*)d_in[2];
  const float* eW_hh = (const float*)d_in[3];
  const float* eb_ih = (const float*)d_in[4];
  const float* eb_hh = (const float*)d_in[5];
  const float* muW   = (const float*)d_in[6];
  const float* mub   = (const float*)d_in[7];
  const float* lvW   = (const float*)d_in[8];
  const float* lvb   = (const float*)d_in[9];
  const float* iW    = (const float*)d_in[10];
  const float* ib    = (const float*)d_in[11];
  const float* dW_ih = (const float*)d_in[12];
  const float* dW_hh = (const float*)d_in[13];
  const float* db_ih = (const float*)d_in[14];
  const float* db_hh = (const float*)d_in[15];
  const float* oW    = (const float*)d_in[16];
  const float* ob    = (const float*)d_in[17];
  float* out = (float*)d_out;
  float* ws  = (float*)d_ws;

  weff_kernel<<<dim3(258), dim3(256), 0, stream>>>(dW_ih, dW_hh, db_ih, db_hh, oW, ob, ws);
  vae_fused<<<dim3(256), dim3(512), 0, stream>>>(
      x, eps, eW_ih, eW_hh, eb_ih, eb_hh, muW, mub, lvW, lvb,
      iW, ib, dW_hh, db_ih, db_hh, oW, ob, ws, out);
}

// Round 13
// 492.367 us; speedup vs baseline: 1.0524x; 1.0524x over previous
//
#include <hip/hip_runtime.h>

#define Bn 512
#define Tn 512
#define Dn 64
#define Hn 128
#define Ln 32
#define GXT   4112            // gx t-stride bytes
#define GXBUF (8*GXT)         // bytes per gx buffer (8 timesteps)
#define HRS   320             // h row stride: row0 -> banks 0-15, row1 -> banks 16-31
#define HBUF  (2*HRS)         // bytes per h buffer
#define SCI  (-1.4426950408889634f)   // -log2(e): i,f,o gate row scale
#define SCG  (-2.8853900817779268f)   // -2 log2(e): g gate row scale / tanh(c) runtime scale

#define EXP2F(v) __builtin_amdgcn_exp2f(v)

typedef __attribute__((ext_vector_type(8))) short short8v;
typedef __attribute__((ext_vector_type(4))) float float4v;
typedef __attribute__((ext_vector_type(2))) float float2v;

__device__ __forceinline__ unsigned short f2bf(float f){
  unsigned int u = __float_as_uint(f);
  u += 0x7FFFu + ((u >> 16) & 1u);           // round-to-nearest-even
  return (unsigned short)(u >> 16);
}

__device__ __forceinline__ short8v pack8(float4v a, float4v b){
  short8v r;
  r[0]=(short)f2bf(a[0]); r[1]=(short)f2bf(a[1]);
  r[2]=(short)f2bf(a[2]); r[3]=(short)f2bf(a[3]);
  r[4]=(short)f2bf(b[0]); r[5]=(short)f2bf(b[1]);
  r[6]=(short)f2bf(b[2]); r[7]=(short)f2bf(b[3]);
  return r;
}

// B-fragment (scaled): lane holds scale*W[n=base+(lane&15)][k0 + 8*(lane>>4) + i]
__device__ __forceinline__ short8v load_wfrag(const float* __restrict__ W, int n, int k0, int ldk, float scale){
  const float* p = W + (size_t)n*(size_t)ldk + (size_t)k0;
  float4v a = *(const float4v*)p;
  float4v b = *(const float4v*)(p+4);
  a *= scale; b *= scale;
  return pack8(a,b);
}

__device__ __forceinline__ float4v mfma16(short8v a, short8v b, float4v c){
  return __builtin_amdgcn_mfma_f32_16x16x32_bf16(a, b, c, 0, 0, 0);
}

// Raw barrier: lgkmcnt-only drain (no vmcnt) so global loads/stores stay in flight.
__device__ __forceinline__ void bar_lds(){
  __builtin_amdgcn_sched_barrier(0);
  asm volatile("s_waitcnt lgkmcnt(0)" ::: "memory");
  __builtin_amdgcn_s_barrier();
  __builtin_amdgcn_sched_barrier(0);
}

// ---------------- precompute: W_eff = dW_hh + dW_ih @ oW ; b_eff = bd + dW_ih @ ob ----------------
__global__ __launch_bounds__(256) void weff_kernel(
    const float* __restrict__ dW_ih, const float* __restrict__ dW_hh,
    const float* __restrict__ db_ih, const float* __restrict__ db_hh,
    const float* __restrict__ oW,    const float* __restrict__ ob,
    float* __restrict__ ws)
{
  int id = blockIdx.x*256 + threadIdx.x;
  if (id < 512*128) {
    int n = id >> 7, h = id & 127;
    float s = dW_hh[id];
    #pragma unroll 8
    for (int d = 0; d < Dn; ++d) s += dW_ih[n*Dn + d] * oW[d*Hn + h];
    ws[id] = s;
  } else if (id < 512*128 + 512) {
    int n = id - 512*128;
    float s = db_ih[n] + db_hh[n];
    #pragma unroll 8
    for (int d = 0; d < Dn; ++d) s += dW_ih[n*Dn + d] * ob[d];
    ws[512*128 + n] = s;
  }
}

// ---------------- main fused kernel: 8 waves, 2 rows/block ----------------
__global__ __launch_bounds__(512, 2) void vae_fused(
    const float* __restrict__ x,     const float* __restrict__ eps,
    const float* __restrict__ eW_ih, const float* __restrict__ eW_hh,
    const float* __restrict__ eb_ih, const float* __restrict__ eb_hh,
    const float* __restrict__ muW,   const float* __restrict__ mub,
    const float* __restrict__ lvW,   const float* __restrict__ lvb,
    const float* __restrict__ iW,    const float* __restrict__ ib,
    const float* __restrict__ dW_hh, const float* __restrict__ db_ih,
    const float* __restrict__ db_hh, const float* __restrict__ oW,
    const float* __restrict__ ob,    const float* __restrict__ ws,
    float* __restrict__ out)
{
  __shared__ __align__(16) char gxb[2*GXBUF];     // ~64 KB: double-buffered gx [t][gate][col][r]
  __shared__ __align__(16) char h_lds[2*HBUF];    // 1.25 KB: double-buffered h, 2 rows @ stride 320
  __shared__ __align__(16) float sc_h[2*Hn];
  __shared__ __align__(16) float sc_mu[2*Ln];
  __shared__ __align__(16) float sc_lv[2*Ln];
  __shared__ __align__(16) float sc_z[2*Ln];

  const int tid  = threadIdx.x;
  const int lane = tid & 63;
  const int w    = tid >> 6;           // wave 0..7: owns h-indices [w*16, w*16+16)
  const int m    = lane & 15;          // fragment col (C) / A row
  const int q    = lane >> 4;          // k-group
  const int hrow = m & 1;              // replicated batch row for h/A reads
  const int rsel = q & 1;              // batch row this lane's nonlin chain owns
  const int jown = w*16 + m;           // h-index this lane owns
  const int b0   = blockIdx.x * 2;
  // per-lane LDS pointers (conflict-free layout)
  char* const hw_p  = h_lds + q*HRS + 2*jown;          // h write (valid q<2; q==rsel there)
  const char* const hr_p = h_lds + hrow*HRS + q*16;    // h-frag read base
  const char* const rgx_p = gxb + jown*8 + rsel*4;     // gx read base (b32: exactly this lane's r)
  char* const gwx_p = gxb + jown*8 + q*(2*GXT);        // gx write base (t=2q)

  // ---- zero h buffers ----
  if (tid < (2*HBUF)/4) ((int*)h_lds)[tid] = 0;

  // ---- encoder weights (gate-scaled): tile nt (=gate) -> row n = nt*128 + jown ----
  short8v wih[8];    // [nt*2+kt] : 4H x D
  short8v whh[16];   // [nt*4+kt] : 4H x H
  #pragma unroll
  for (int nt = 0; nt < 4; ++nt) {
    const float sc = (nt == 2) ? SCG : SCI;
    #pragma unroll
    for (int kt = 0; kt < 2; ++kt) wih[nt*2+kt] = load_wfrag(eW_ih, nt*128 + jown, kt*32 + q*8, Dn, sc);
    #pragma unroll
    for (int kt = 0; kt < 4; ++kt) whh[nt*4+kt] = load_wfrag(eW_hh, nt*128 + jown, kt*32 + q*8, Hn, sc);
  }
  float bia[4];
  #pragma unroll
  for (int g = 0; g < 4; ++g)
    bia[g] = (eb_ih[g*128 + jown] + eb_hh[g*128 + jown]) * ((g == 2) ? SCG : SCI);

  // ---- x batch registers: lane (m,q) holds x[b0+(m&1)][tb*8 + (m>>1)][q*8 ..+8, +32..] ----
  const float* xptr = x + (size_t)(b0 + hrow)*Tn*Dn + (size_t)(m>>1)*Dn + q*8;
  float4v xc0,xc1,xc2,xc3, xn0,xn1,xn2,xn3;
  xc0 = *(const float4v*)(xptr+0);  xc1 = *(const float4v*)(xptr+4);
  xc2 = *(const float4v*)(xptr+32); xc3 = *(const float4v*)(xptr+36);
  xptr += 512;                       // now points at tb=1
  int xnext = 1;                     // next tb to load

  float cst = 0.f, hval = 0.f;       // per-lane c/h for (rsel, jown)
  __syncthreads();

#define RH(RB,KB)    (*(const short8v*)(hr_p + (RB)*HBUF + (KB)))
#define RGX(CB,S,NT) (*(const float*)(rgx_p + (CB)*GXBUF + (S)*GXT + (NT)*1024))

  // gx batch for the NEXT 8-step window into buffer PB (bias pre-added; gate-scaled
  // because wih/bia are scaled). C row q*4+j -> (t = 2q+(j>>1), r = j&1).
#define BATCH(PB) do { \
    short8v xf0 = pack8(xc0, xc1); \
    short8v xf1 = pack8(xc2, xc3); \
    if (xnext < 64) { \
      xn0 = *(const float4v*)(xptr+0);  xn1 = *(const float4v*)(xptr+4); \
      xn2 = *(const float4v*)(xptr+32); xn3 = *(const float4v*)(xptr+36); \
      xptr += 512; \
    } \
    ++xnext; \
    float4v zz = {0.f,0.f,0.f,0.f}; \
    __builtin_amdgcn_s_setprio(1); \
    float4v c0_ = mfma16(xf0, wih[0], zz); \
    float4v c1_ = mfma16(xf0, wih[2], zz); \
    float4v c2_ = mfma16(xf0, wih[4], zz); \
    float4v c3_ = mfma16(xf0, wih[6], zz); \
    c0_ = mfma16(xf1, wih[1], c0_); \
    c1_ = mfma16(xf1, wih[3], c1_); \
    c2_ = mfma16(xf1, wih[5], c2_); \
    c3_ = mfma16(xf1, wih[7], c3_); \
    __builtin_amdgcn_s_setprio(0); \
    char* gp = gwx_p + (PB)*GXBUF; \
    *(float2v*)(gp +       0) = (float2v){c0_[0]+bia[0], c0_[1]+bia[0]}; \
    *(float2v*)(gp +    1024) = (float2v){c1_[0]+bia[1], c1_[1]+bia[1]}; \
    *(float2v*)(gp +    2048) = (float2v){c2_[0]+bia[2], c2_[1]+bia[2]}; \
    *(float2v*)(gp +    3072) = (float2v){c3_[0]+bia[3], c3_[1]+bia[3]}; \
    *(float2v*)(gp + GXT +    0) = (float2v){c0_[2]+bia[0], c0_[3]+bia[0]}; \
    *(float2v*)(gp + GXT + 1024) = (float2v){c1_[2]+bia[1], c1_[3]+bia[1]}; \
    *(float2v*)(gp + GXT + 2048) = (float2v){c2_[2]+bia[2], c2_[3]+bia[2]}; \
    *(float2v*)(gp + GXT + 3072) = (float2v){c3_[2]+bia[3], c3_[3]+bia[3]}; \
    xc0=xn0; xc1=xn1; xc2=xn2; xc3=xn3; \
  } while(0)

  // ONE chain per lane; gates arrive PRE-SCALED: sigm = rcp(1+exp2(g')), tanh = 2*rcp(1+exp2(g''))-1.
#define NONLIN1(GI,GF,GG,GO, WB) do { \
    float si = __builtin_amdgcn_rcpf(1.0f + EXP2F(GI)); \
    float sf = __builtin_amdgcn_rcpf(1.0f + EXP2F(GF)); \
    float so = __builtin_amdgcn_rcpf(1.0f + EXP2F(GO)); \
    float tg = 2.0f*__builtin_amdgcn_rcpf(1.0f + EXP2F(GG)) - 1.0f; \
    float c = sf*cst + si*tg; \
    cst = c; \
    float tc = 2.0f*__builtin_amdgcn_rcpf(1.0f + EXP2F(c*SCG)) - 1.0f; \
    hval = so*tc; \
    if (q < 2) *(unsigned short*)(hw_p + (WB)*HBUF) = f2bf(hval); \
  } while(0)

  // gate MFMAs with C initialized from I0..I3 (zero or loop-invariant bias splat)
#define HH16(RB, I0,I1,I2,I3) \
    short8v hf0 = RH(RB,0), hf1 = RH(RB,64), hf2 = RH(RB,128), hf3 = RH(RB,192); \
    __builtin_amdgcn_s_setprio(1); \
    float4v a0 = mfma16(hf0, whh[0],  I0); \
    float4v a1 = mfma16(hf0, whh[4],  I1); \
    float4v a2 = mfma16(hf0, whh[8],  I2); \
    float4v a3 = mfma16(hf0, whh[12], I3); \
    a0 = mfma16(hf1, whh[1],  a0); a1 = mfma16(hf1, whh[5],  a1); \
    a2 = mfma16(hf1, whh[9],  a2); a3 = mfma16(hf1, whh[13], a3); \
    a0 = mfma16(hf2, whh[2],  a0); a1 = mfma16(hf2, whh[6],  a1); \
    a2 = mfma16(hf2, whh[10], a2); a3 = mfma16(hf2, whh[14], a3); \
    a0 = mfma16(hf3, whh[3],  a0); a1 = mfma16(hf3, whh[7],  a1); \
    a2 = mfma16(hf3, whh[11], a2); a3 = mfma16(hf3, whh[15], a3); \
    __builtin_amdgcn_s_setprio(0);

  // Encoder: gx added POST-MFMA (round-10 structure) so the gx ds_read latency
  // overlaps the MFMA chain instead of gating it.
#define ENC_BODY(S, CB) \
    float g0 = RGX(CB,S,0), g1 = RGX(CB,S,1), g2 = RGX(CB,S,2), g3 = RGX(CB,S,3); \
    float4v z4 = {0.f,0.f,0.f,0.f}; \
    HH16((S)&1, z4,z4,z4,z4); \
    float gi = (rsel ? a0[1] : a0[0]) + g0; \
    float gf = (rsel ? a1[1] : a1[0]) + g1; \
    float gg = (rsel ? a2[1] : a2[0]) + g2; \
    float go = (rsel ? a3[1] : a3[0]) + g3;

#define ENC_STEP(S, CB) do { \
    ENC_BODY(S, CB); \
    NONLIN1(gi, gf, gg, go, ((S)&1)^1); \
    bar_lds(); \
  } while(0)

#define ENC_STEP0(CB, PRODUCE) do { \
    ENC_BODY(0, CB); \
    NONLIN1(gi, gf, gg, go, 1); \
    if (PRODUCE) BATCH((CB)^1); \
    bar_lds(); \
  } while(0)

#define ENC8(CB, PRODUCE) do { \
    ENC_STEP0(CB, PRODUCE); \
    ENC_STEP(1,CB); ENC_STEP(2,CB); ENC_STEP(3,CB); \
    ENC_STEP(4,CB); ENC_STEP(5,CB); ENC_STEP(6,CB); ENC_STEP(7,CB); \
  } while(0)

  // ================= encoder: 64 batches x 8 steps =================
  BATCH(0);            // gx(tb=0) -> buf0; loads x(tb=1)
  bar_lds();
  #pragma unroll 1
  for (int tb2 = 0; tb2 < 32; ++tb2) {
    ENC8(0, 1);                  // consume buf0, produce buf1
    ENC8(1, (tb2 < 31));         // consume buf1, produce buf0, skip last
  }
  // final h in buffer 0; exact f32 copy of owned element in hval (lanes q<2)

  // ================= latent =================
  if (q < 2) sc_h[rsel*Hn + jown] = hval;
  __syncthreads();

  if (tid < 128) {
    const int isLv = tid >> 6;
    const int rr   = (tid >> 5) & 1;
    const int l    = tid & 31;
    const float* Wp = isLv ? lvW : muW;
    float s = isLv ? lvb[l] : mub[l];
    #pragma unroll
    for (int k = 0; k < Hn; k += 4) {
      float4v wv = *(const float4v*)(Wp + l*Hn + k);
      float4v hv = *(const float4v*)(sc_h + rr*Hn + k);
      s += wv[0]*hv[0] + wv[1]*hv[1] + wv[2]*hv[2] + wv[3]*hv[3];
    }
    out[(size_t)Bn*Tn*Dn + (size_t)isLv*Bn*Ln + (size_t)(b0+rr)*Ln + l] = s;
    (isLv ? sc_lv : sc_mu)[rr*Ln + l] = s;
  }
  __syncthreads();

  if (tid < 64) {
    int rr = tid >> 5, l = tid & 31;
    sc_z[rr*Ln+l] = sc_mu[rr*Ln+l] + eps[(size_t)(b0+rr)*Ln + l] * __expf(0.5f * sc_lv[rr*Ln+l]);
  }
  __syncthreads();

  if (tid < 256) { // decoder hidden init (unscaled, it's h not a gate) -> h buffer 0
    int rr = tid >> 7, jj = tid & 127;
    float s = ib[jj];
    #pragma unroll
    for (int l = 0; l < Ln; ++l) s += sc_z[rr*Ln + l] * iW[jj*Ln + l];
    *(unsigned short*)(h_lds + rr*HRS + 2*jj) = f2bf(s);
  }
  cst = 0.f;

  // ---- decoder step-0 weights (dW_hh, bd; gate-scaled) + output-proj fragments (unscaled) ----
  #pragma unroll
  for (int nt = 0; nt < 4; ++nt) {
    const float sc = (nt == 2) ? SCG : SCI;
    #pragma unroll
    for (int kt = 0; kt < 4; ++kt) whh[nt*4+kt] = load_wfrag(dW_hh, nt*128 + jown, kt*32 + q*8, Hn, sc);
  }
  float dbia[4];
  #pragma unroll
  for (int g = 0; g < 4; ++g)
    dbia[g] = (db_ih[g*128 + jown] + db_hh[g*128 + jown]) * ((g == 2) ? SCG : SCI);
  const int ocol = (w & 3)*16 + m;
  short8v ow0 = load_wfrag(oW, ocol,  0 + q*8, Hn, 1.0f);
  short8v ow1 = load_wfrag(oW, ocol, 32 + q*8, Hn, 1.0f);
  short8v ow2 = load_wfrag(oW, ocol, 64 + q*8, Hn, 1.0f);
  short8v ow3 = load_wfrag(oW, ocol, 96 + q*8, Hn, 1.0f);
  const float obv = ob[ocol];
  const float4v ob4 = {obv, obv, obv, obv};
  __syncthreads();

  // ---- decoder step 0: gates = h0 @ dW_hh^T + bd (input is zero) ----
  {
    float4v t0 = {dbia[0],dbia[0],dbia[0],dbia[0]};
    float4v t1 = {dbia[1],dbia[1],dbia[1],dbia[1]};
    float4v t2 = {dbia[2],dbia[2],dbia[2],dbia[2]};
    float4v t3 = {dbia[3],dbia[3],dbia[3],dbia[3]};
    HH16(0, t0,t1,t2,t3);
    float gi = rsel ? a0[1] : a0[0];
    float gf = rsel ? a1[1] : a1[0];
    float gg = rsel ? a2[1] : a2[0];
    float go = rsel ? a3[1] : a3[0];
    NONLIN1(gi, gf, gg, go, 1);
    bar_lds();
  }

  // ---- switch to folded weights: W_eff = dW_hh + dW_ih@oW ; b_eff (gate-scaled) ----
  {
    const float* weff = ws;
    const float* beff = ws + 512*128;
    #pragma unroll
    for (int nt = 0; nt < 4; ++nt) {
      const float sc = (nt == 2) ? SCG : SCI;
      #pragma unroll
      for (int kt = 0; kt < 4; ++kt) whh[nt*4+kt] = load_wfrag(weff, nt*128 + jown, kt*32 + q*8, Hn, sc);
    }
    #pragma unroll
    for (int g = 0; g < 4; ++g) dbia[g] = beff[g*128 + jown] * ((g == 2) ? SCG : SCI);
  }
  const float4v cb0 = {dbia[0],dbia[0],dbia[0],dbia[0]};
  const float4v cb1 = {dbia[1],dbia[1],dbia[1],dbia[1]};
  const float4v cb2 = {dbia[2],dbia[2],dbia[2],dbia[2]};
  const float4v cb3 = {dbia[3],dbia[3],dbia[3],dbia[3]};

  float* outp0 = out + (size_t)(b0+0)*Tn*Dn;
  float* outp1 = out + (size_t)(b0+1)*Tn*Dn;

  // y-MFMAs issue right after gate MFMAs (pipe stays fed while gate latency drains);
  // nonlin runs while y-MFMAs complete; store after.
#define DEC_STEP(RB) do { \
    HH16(RB, cb0,cb1,cb2,cb3); \
    float4v ya = ob4; \
    if (w < 4) { \
      __builtin_amdgcn_s_setprio(1); \
      ya = mfma16(hf0, ow0, ya); ya = mfma16(hf1, ow1, ya); \
      ya = mfma16(hf2, ow2, ya); ya = mfma16(hf3, ow3, ya); \
      __builtin_amdgcn_s_setprio(0); \
    } \
    float gi = rsel ? a0[1] : a0[0]; \
    float gf = rsel ? a1[1] : a1[0]; \
    float gg = rsel ? a2[1] : a2[0]; \
    float go = rsel ? a3[1] : a3[0]; \
    NONLIN1(gi, gf, gg, go, (RB)^1); \
    if (w < 4 && q == 0) { outp0[ocol] = ya[0]; outp1[ocol] = ya[1]; } \
    outp0 += Dn; outp1 += Dn; \
    bar_lds(); \
  } while(0)

  // ---- decoder steps 1..511; y(i-1) computed from the same h(i) fragments ----
  #pragma unroll 1
  for (int i = 1; i < Tn-1; i += 2) {
    DEC_STEP(1);
    DEC_STEP(0);
  }
  DEC_STEP(1);

  // ---- epilogue: y(511) from h(512) (buffer 0) ----
  if (w < 4) {
    short8v hf0 = RH(0,0), hf1 = RH(0,64), hf2 = RH(0,128), hf3 = RH(0,192);
    float4v ya = ob4;
    ya = mfma16(hf0, ow0, ya); ya = mfma16(hf1, ow1, ya);
    ya = mfma16(hf2, ow2, ya); ya = mfma16(hf3, ow3, ya);
    if (q == 0) {
      outp0[ocol] = ya[0];
      outp1[ocol] = ya[1];
    }
  }
#undef DEC_STEP
#undef ENC8
#undef ENC_STEP0
#undef ENC_STEP
#undef ENC_BODY
#undef HH16
#undef NONLIN1
#undef BATCH
#undef RGX
#undef RH
}

extern "C" void kernel_launch(void* const* d_in, const int* in_sizes, int n_in,
                              void* d_out, int out_size, void* d_ws, size_t ws_size,
                              hipStream_t stream) {
  (void)in_sizes; (void)n_in; (void)ws_size; (void)out_size;
  const float* x     = (const float*)d_in[0];
  const float* eps   = (const float*)d_in[1];
  const float* eW_ih = (const float*)d_in[2];
  const float* eW_hh = (const float*)d_in[3];
  const float* eb_ih = (const float*)d_in[4];
  const float* eb_hh = (const float*)d_in[5];
  const float* muW   = (const float*)d_in[6];
  const float* mub   = (const float*)d_in[7];
  const float* lvW   = (const float*)d_in[8];
  const float* lvb   = (const float*)d_in[9];
  const float* iW    = (const float*)d_in[10];
  const float* ib    = (const float*)d_in[11];
  const float* dW_ih = (const float*)d_in[12];
  const float* dW_hh = (const float*)d_in[13];
  const float* db_ih = (const float*)d_in[14];
  const float* db_hh = (const float*)d_in[15];
  const float* oW    = (const float*)d_in[16];
  const float* ob    = (const float*)d_in[17];
  float* out = (float*)d_out;
  float* ws  = (float*)d_ws;

  weff_kernel<<<dim3(258), dim3(256), 0, stream>>>(dW_ih, dW_hh, db_ih, db_hh, oW, ob, ws);
  vae_fused<<<dim3(256), dim3(512), 0, stream>>>(
      x, eps, eW_ih, eW_hh, eb_ih, eb_hh, muW, mub, lvW, lvb,
      iW, ib, dW_hh, db_ih, db_hh, oW, ob, ws, out);
}